// Round 3
// baseline (207.718 us; speedup 1.0000x reference)
//
#include <hip/hip_runtime.h>

typedef short short8 __attribute__((ext_vector_type(8)));
typedef float f32x4  __attribute__((ext_vector_type(4)));

constexpr int M_TOT  = 8 * 4096;   // 32768 pixels
constexpr int K_PROT = 1024;
constexpr int D_DIM  = 128;

// ws layout: psq @0 (4 KB), pfrag @4K (512 KB)
constexpr size_t WS_PF_OFF = (size_t)K_PROT * 4;

__device__ inline unsigned short bf16_hi(float f) {
  unsigned u = __builtin_bit_cast(unsigned, f);
  unsigned r = u + 0x7FFFu + ((u >> 16) & 1u);   // RNE
  return (unsigned short)(r >> 16);
}
__device__ inline float bf16_tof(unsigned short h) {
  return __builtin_bit_cast(float, (unsigned)h << 16);
}

// LDS-only barrier: ds ops complete (lgkmcnt), but do NOT drain in-flight
// global nontemporal stores (vmcnt) like __syncthreads() would.
__device__ inline void barrier_lds() {
  asm volatile("s_waitcnt lgkmcnt(0)\n\ts_barrier" ::: "memory");
}

// ---------------------------------------------------------------------------
// psq only (xsq is now computed inside proto_mfma from the staged x tile).
__global__ __launch_bounds__(256) void psq_kernel(
    const float* __restrict__ p, float* __restrict__ psq) {
  int group = blockIdx.x * 8 + (threadIdx.x >> 5);
  int lane  = threadIdx.x & 31;
  if (group >= K_PROT) return;
  float4 v = reinterpret_cast<const float4*>(p + (size_t)group * D_DIM)[lane];
  float s = v.x * v.x + v.y * v.y + v.z * v.z + v.w * v.w;
  #pragma unroll
  for (int off = 16; off > 0; off >>= 1) s += __shfl_down(s, off, 32);
  if (lane == 0) psq[group] = s;
}

// ---------------------------------------------------------------------------
// Pre-swizzle protos into MFMA A-fragment order, bf16 hi/lo split.
// g in [0,32768): ng=g>>9 (16-proto group), slot=(g>>6)&7 (part*4+ks), lane=g&63.
// Element: proto = ng*16 + (lane&15), k = ks*32 + (lane>>4)*8 + j.
// Grid MUST be 32768/256 = 128 blocks.
__global__ __launch_bounds__(256) void pfrag_kernel(
    const float* __restrict__ p, short* __restrict__ pf) {
  int g    = blockIdx.x * 256 + threadIdx.x;
  int lane = g & 63;
  int s    = (g >> 6) & 7;
  int ng   = g >> 9;
  int part = s >> 2, ks = s & 3;
  int proto = ng * 16 + (lane & 15);
  int k0    = ks * 32 + (lane >> 4) * 8;
  const float4* pr = (const float4*)(p + (size_t)proto * D_DIM + k0);
  float4 a = pr[0], b = pr[1];
  float e[8] = {a.x, a.y, a.z, a.w, b.x, b.y, b.z, b.w};
  short8 frag;
  #pragma unroll
  for (int j = 0; j < 8; ++j) {
    unsigned short h = bf16_hi(e[j]);
    if (part) h = bf16_hi(e[j] - bf16_tof(h));
    frag[j] = (short)h;
  }
  *(short8*)(pf + (size_t)g * 8) = frag;
}

// ---------------------------------------------------------------------------
// Main: A=protos (global frags, L2-hot), B=pixels (LDS frags). Block = 64 pix,
// 4 waves; wave w covers protos [chunk*256 + w*64, +64) over 4 chunks.
// C/D: col(lane&15)=pixel, row=(lane>>4)*4+reg = 4 consecutive protos.
// R3: 3 blocks/CU (LDS 50.8 KB, launch_bounds(256,3)) for latency hiding;
// score staging in 16-pixel rounds -> 1 KB contiguous store segments, all
// 4 waves participate in staging; xsq computed in-block from the staged tile.
__global__ __launch_bounds__(256, 3) void proto_mfma(
    const float* __restrict__ x, const float* __restrict__ p,
    const short* __restrict__ pf, const float* __restrict__ psq,
    float* __restrict__ matched, float* __restrict__ scores) {
  __shared__ short xlds[32 * 64 * 8];   // 32 KB: [part*16 + nt*4 + ks][lane][8]
  __shared__ float sbuf[16][260];       // 16.6 KB score staging (also aliased as xpart)
  __shared__ float sv[4][64];
  __shared__ int   si[4][64];
  __shared__ int   fidx[64];
  __shared__ float xsqv[64];

  const int tid = threadIdx.x;
  const int w   = tid >> 6;
  const int l   = tid & 63;
  const int m0  = blockIdx.x * 64;

  // xpart alias: [pixel 0..63][16 partials] = 4 KB inside sbuf (sbuf unused yet)
  float (*xpart)[16] = (float(*)[16])&sbuf[0][0];

  // ---- stage x tile into LDS in B-fragment order, hi/lo split (once) ----
  // piece = i*256+tid -> lane=l, s=i*4+w -> ks=w, nt=i&3, part=i>>2.
  #pragma unroll
  for (int i = 0; i < 8; ++i) {
    int piece = i * 256 + tid;          // 0..2047
    int s = piece >> 6;                 // 0..31
    int ks = s & 3, nt = (s >> 2) & 3, part = s >> 4;
    int pix = m0 + nt * 16 + (l & 15);
    int k0  = ks * 32 + (l >> 4) * 8;
    const float4* xr = (const float4*)(x + (size_t)pix * D_DIM + k0);
    float4 a = xr[0], b = xr[1];
    float e[8] = {a.x, a.y, a.z, a.w, b.x, b.y, b.z, b.w};
    if (part == 0) {  // each (pix,k) octet appears exactly once with part==0
      float ss = e[0]*e[0] + e[1]*e[1] + e[2]*e[2] + e[3]*e[3]
               + e[4]*e[4] + e[5]*e[5] + e[6]*e[6] + e[7]*e[7];
      xpart[nt * 16 + (l & 15)][ks * 4 + (l >> 4)] = ss;
    }
    short8 frag;
    #pragma unroll
    for (int j = 0; j < 8; ++j) {
      unsigned short h = bf16_hi(e[j]);
      if (part) h = bf16_hi(e[j] - bf16_tof(h));
      frag[j] = (short)h;
    }
    *(short8*)(xlds + (size_t)piece * 8) = frag;
  }
  __syncthreads();

  if (tid < 64) {
    float s = 0.f;
    #pragma unroll
    for (int j = 0; j < 16; ++j) s += xpart[tid][j];
    xsqv[tid] = s;
  }
  __syncthreads();   // xsqv ready; sbuf free for score staging after this

  float xs[4];
  #pragma unroll
  for (int nt = 0; nt < 4; ++nt) xs[nt] = xsqv[nt * 16 + (l & 15)];

  float best[4]; int bidx[4];
  #pragma unroll
  for (int nt = 0; nt < 4; ++nt) { best[nt] = -3.4e38f; bidx[nt] = 0; }

  for (int chunk = 0; chunk < 4; ++chunk) {
    f32x4 acc[4][4];
    #pragma unroll
    for (int mt = 0; mt < 4; ++mt)
      #pragma unroll
      for (int nt = 0; nt < 4; ++nt) acc[mt][nt] = (f32x4){0.f, 0.f, 0.f, 0.f};

    const int pgbase = chunk * 16 + w * 4;

    #pragma unroll
    for (int ks = 0; ks < 4; ++ks) {
      short8 pah[4], pal[4], bh[4], bl[4];
      #pragma unroll
      for (int mt = 0; mt < 4; ++mt) {
        pah[mt] = *(const short8*)(pf + ((size_t)((pgbase + mt) * 8 + ks) * 64 + l) * 8);
        pal[mt] = *(const short8*)(pf + ((size_t)((pgbase + mt) * 8 + 4 + ks) * 64 + l) * 8);
      }
      #pragma unroll
      for (int nt = 0; nt < 4; ++nt) {
        bh[nt] = *(const short8*)(xlds + (size_t)(((nt * 4 + ks) * 64) + l) * 8);
        bl[nt] = *(const short8*)(xlds + (size_t)(((16 + nt * 4 + ks) * 64) + l) * 8);
      }
      #pragma unroll
      for (int mt = 0; mt < 4; ++mt)
        #pragma unroll
        for (int nt = 0; nt < 4; ++nt)
          acc[mt][nt] = __builtin_amdgcn_mfma_f32_16x16x32_bf16(pah[mt], bh[nt], acc[mt][nt], 0, 0, 0);
      #pragma unroll
      for (int mt = 0; mt < 4; ++mt)
        #pragma unroll
        for (int nt = 0; nt < 4; ++nt)
          acc[mt][nt] = __builtin_amdgcn_mfma_f32_16x16x32_bf16(pah[mt], bl[nt], acc[mt][nt], 0, 0, 0);
      #pragma unroll
      for (int mt = 0; mt < 4; ++mt)
        #pragma unroll
        for (int nt = 0; nt < 4; ++nt)
          acc[mt][nt] = __builtin_amdgcn_mfma_f32_16x16x32_bf16(pal[mt], bh[nt], acc[mt][nt], 0, 0, 0);
    }

    // ---- transform acc in place to final score values + running argmax ----
    // o = fmaf(2, xp, -(xs+psq)) == -((xs+psq) - 2*xp) bit-exact (mod +-0).
    #pragma unroll
    for (int mt = 0; mt < 4; ++mt) {
      int pbase = chunk * 256 + w * 64 + mt * 16 + (l >> 4) * 4;
      float psa[4];
      *(float4*)psa = *(const float4*)(psq + pbase);
      #pragma unroll
      for (int nt = 0; nt < 4; ++nt) {
        f32x4 o;
        {
          #pragma clang fp contract(off)
          #pragma unroll
          for (int r = 0; r < 4; ++r) {
            float s = xs[nt] + psa[r];
            o[r] = __builtin_fmaf(2.0f, acc[mt][nt][r], -s);
            if (o[r] > best[nt]) { best[nt] = o[r]; bidx[nt] = pbase + r; }
          }
        }
        acc[mt][nt] = o;   // acc now holds final scores
      }
    }

    // ---- 4 staging+store rounds (16 pixels each); all waves stage;
    //      drain = one 1 KB contiguous segment per wave instruction ----
    #pragma unroll
    for (int r = 0; r < 4; ++r) {
      #pragma unroll
      for (int mt = 0; mt < 4; ++mt)
        *(f32x4*)&sbuf[l & 15][(w << 6) + mt * 16 + ((l >> 4) << 2)] = acc[mt][r];
      barrier_lds();
      #pragma unroll
      for (int ps = 0; ps < 4; ++ps) {
        int row = ps * 4 + w;          // 0..15
        f32x4 v = *(const f32x4*)&sbuf[row][l << 2];
        __builtin_nontemporal_store(v,
            (f32x4*)(scores + (size_t)(m0 + r * 16 + row) * K_PROT + chunk * 256) + l);
      }
      barrier_lds();   // readers done before next round's writers overwrite sbuf
    }
  }

  // ---- argmax reduce: butterfly over quads, then LDS over waves ----
  #pragma unroll
  for (int nt = 0; nt < 4; ++nt) {
    #pragma unroll
    for (int m = 16; m <= 32; m <<= 1) {
      float ov = __shfl_xor(best[nt], m);
      int   oi = __shfl_xor(bidx[nt], m);
      if (ov > best[nt] || (ov == best[nt] && oi < bidx[nt])) {
        best[nt] = ov; bidx[nt] = oi;
      }
    }
  }
  if (l < 16) {
    #pragma unroll
    for (int nt = 0; nt < 4; ++nt) {
      sv[w][nt * 16 + l] = best[nt];
      si[w][nt * 16 + l] = bidx[nt];
    }
  }
  __syncthreads();
  if (tid < 64) {
    float v = sv[0][tid]; int bi = si[0][tid];
    #pragma unroll
    for (int e = 1; e < 4; ++e) {
      float vv = sv[e][tid]; int ii = si[e][tid];
      if (vv > v || (vv == v && ii < bi)) { v = vv; bi = ii; }
    }
    fidx[tid] = bi;
  }
  __syncthreads();

  // ---- gather matched = original fp32 prototypes[argmax] ----
  for (int q = tid; q < 64 * 32; q += 256) {
    int pix = q >> 5, f4 = q & 31;
    float4 v = ((const float4*)(p + (size_t)fidx[pix] * D_DIM))[f4];
    __builtin_nontemporal_store(*(f32x4*)&v,
        (f32x4*)(matched + (size_t)(m0 + pix) * D_DIM) + f4);
  }
}

// ---------------------------------------------------------------------------
extern "C" void kernel_launch(void* const* d_in, const int* in_sizes, int n_in,
                              void* d_out, int out_size, void* d_ws, size_t ws_size,
                              hipStream_t stream) {
  const float* x = (const float*)d_in[0];   // [B,N,D] fp32
  const float* p = (const float*)d_in[1];   // [K,D]   fp32

  float* matched = (float*)d_out;                            // [B,N,D]
  float* scores  = (float*)d_out + (size_t)M_TOT * D_DIM;    // [B,N,K]

  float* psq = (float*)d_ws;
  short* pf  = (short*)((char*)d_ws + WS_PF_OFF);

  psq_kernel<<<K_PROT / 8, 256, 0, stream>>>(p, psq);
  pfrag_kernel<<<128, 256, 0, stream>>>(p, pf);              // 32768 frags / 256
  proto_mfma<<<M_TOT / 64, 256, 0, stream>>>(x, p, pf, psq, matched, scores);
}

// Round 4
// 207.148 us; speedup vs baseline: 1.0027x; 1.0027x over previous
//
#include <hip/hip_runtime.h>

typedef short short8 __attribute__((ext_vector_type(8)));
typedef float f32x4  __attribute__((ext_vector_type(4)));

constexpr int M_TOT  = 8 * 4096;   // 32768 pixels
constexpr int K_PROT = 1024;
constexpr int D_DIM  = 128;

// ws layout: psq @0 (4 KB), pfrag @4K (512 KB)
constexpr size_t WS_PF_OFF = (size_t)K_PROT * 4;

__device__ inline unsigned short bf16_hi(float f) {
  unsigned u = __builtin_bit_cast(unsigned, f);
  unsigned r = u + 0x7FFFu + ((u >> 16) & 1u);   // RNE
  return (unsigned short)(r >> 16);
}
__device__ inline float bf16_tof(unsigned short h) {
  return __builtin_bit_cast(float, (unsigned)h << 16);
}

// LDS-only barrier: ds ops complete (lgkmcnt), but do NOT drain in-flight
// global nontemporal stores (vmcnt) like __syncthreads() would.
__device__ inline void barrier_lds() {
  asm volatile("s_waitcnt lgkmcnt(0)\n\ts_barrier" ::: "memory");
}

// ---------------------------------------------------------------------------
// psq only (xsq is computed inside proto_mfma from the staged x tile).
__global__ __launch_bounds__(256) void psq_kernel(
    const float* __restrict__ p, float* __restrict__ psq) {
  int group = blockIdx.x * 8 + (threadIdx.x >> 5);
  int lane  = threadIdx.x & 31;
  if (group >= K_PROT) return;
  float4 v = reinterpret_cast<const float4*>(p + (size_t)group * D_DIM)[lane];
  float s = v.x * v.x + v.y * v.y + v.z * v.z + v.w * v.w;
  #pragma unroll
  for (int off = 16; off > 0; off >>= 1) s += __shfl_down(s, off, 32);
  if (lane == 0) psq[group] = s;
}

// ---------------------------------------------------------------------------
// Pre-swizzle protos into MFMA A-fragment order, bf16 hi/lo split.
// g in [0,32768): ng=g>>9 (16-proto group), slot=(g>>6)&7 (part*4+ks), lane=g&63.
// Element: proto = ng*16 + (lane&15), k = ks*32 + (lane>>4)*8 + j.
// Grid MUST be 32768/256 = 128 blocks.
__global__ __launch_bounds__(256) void pfrag_kernel(
    const float* __restrict__ p, short* __restrict__ pf) {
  int g    = blockIdx.x * 256 + threadIdx.x;
  int lane = g & 63;
  int s    = (g >> 6) & 7;
  int ng   = g >> 9;
  int part = s >> 2, ks = s & 3;
  int proto = ng * 16 + (lane & 15);
  int k0    = ks * 32 + (lane >> 4) * 8;
  const float4* pr = (const float4*)(p + (size_t)proto * D_DIM + k0);
  float4 a = pr[0], b = pr[1];
  float e[8] = {a.x, a.y, a.z, a.w, b.x, b.y, b.z, b.w};
  short8 frag;
  #pragma unroll
  for (int j = 0; j < 8; ++j) {
    unsigned short h = bf16_hi(e[j]);
    if (part) h = bf16_hi(e[j] - bf16_tof(h));
    frag[j] = (short)h;
  }
  *(short8*)(pf + (size_t)g * 8) = frag;
}

// ---------------------------------------------------------------------------
// R4: block = 16 pixels (grid 2048), all 1024 protos' scores for the block's
// pixels accumulate in a 33 KB LDS buffer; two drains write each score row in
// 2 KB contiguous runs (block-linear, fill-like HBM pattern) instead of eight
// scattered 512 B visits per row. 4 barrier pairs/block total in the K loop.
// A=protos (pf, L2-hot), B=pixels (LDS). C/D: col(lane&15)=pixel,
// row=(lane>>4)*4+reg = 4 consecutive protos.
__global__ __launch_bounds__(256, 2) void proto_mfma(
    const float* __restrict__ x, const float* __restrict__ p,
    const short* __restrict__ pf, const float* __restrict__ psq,
    float* __restrict__ matched, float* __restrict__ scores) {
  __shared__ short xlds[8 * 64 * 8];    // 8 KB: [part*4 + ks][lane][8]
  __shared__ float sbuf[16][520];       // 33.3 KB: [pixel][512 scores + 8 pad]
  __shared__ float sv[4][16];
  __shared__ int   si[4][16];
  __shared__ int   fidx[16];
  __shared__ float xsqv[16];

  const int tid = threadIdx.x;
  const int w   = tid >> 6;
  const int l   = tid & 63;
  const int m0  = blockIdx.x * 16;

  // xpart alias: [pixel 0..15][16 partials] = 1 KB inside sbuf (unused yet)
  float (*xpart)[16] = (float(*)[16])&sbuf[0][0];

  // ---- stage x tile (16 pix x 128 d) into LDS, B-frag order, hi/lo ----
  // i = part; ks = w; k0 = w*32 + (l>>4)*8.
  #pragma unroll
  for (int i = 0; i < 2; ++i) {
    int pix = m0 + (l & 15);
    int k0  = w * 32 + (l >> 4) * 8;
    const float4* xr = (const float4*)(x + (size_t)pix * D_DIM + k0);
    float4 a = xr[0], b = xr[1];
    float e[8] = {a.x, a.y, a.z, a.w, b.x, b.y, b.z, b.w};
    if (i == 0) {
      float ss = e[0]*e[0] + e[1]*e[1] + e[2]*e[2] + e[3]*e[3]
               + e[4]*e[4] + e[5]*e[5] + e[6]*e[6] + e[7]*e[7];
      xpart[l & 15][w * 4 + (l >> 4)] = ss;
    }
    short8 frag;
    #pragma unroll
    for (int j = 0; j < 8; ++j) {
      unsigned short h = bf16_hi(e[j]);
      if (i) h = bf16_hi(e[j] - bf16_tof(h));
      frag[j] = (short)h;
    }
    *(short8*)(xlds + (size_t)((i * 4 + w) * 64 + l) * 8) = frag;
  }
  __syncthreads();

  if (tid < 16) {
    float s = 0.f;
    #pragma unroll
    for (int j = 0; j < 16; ++j) s += xpart[tid][j];
    xsqv[tid] = s;
  }
  __syncthreads();   // xsqv ready; sbuf free for score staging after this

  const float xs = xsqv[l & 15];   // this lane's pixel norm (col = lane&15)

  float best = -3.4e38f;
  int   bidx = 0;

  for (int half = 0; half < 2; ++half) {
    #pragma unroll
    for (int ci = 0; ci < 2; ++ci) {
      const int chunk  = half * 2 + ci;
      const int pgbase = chunk * 16 + w * 4;

      f32x4 acc[4];
      #pragma unroll
      for (int mt = 0; mt < 4; ++mt) acc[mt] = (f32x4){0.f, 0.f, 0.f, 0.f};

      #pragma unroll
      for (int ks = 0; ks < 4; ++ks) {
        short8 pah[4], pal[4];
        #pragma unroll
        for (int mt = 0; mt < 4; ++mt) {
          pah[mt] = *(const short8*)(pf + ((size_t)((pgbase + mt) * 8 + ks) * 64 + l) * 8);
          pal[mt] = *(const short8*)(pf + ((size_t)((pgbase + mt) * 8 + 4 + ks) * 64 + l) * 8);
        }
        short8 bh = *(const short8*)(xlds + (size_t)((ks) * 64 + l) * 8);
        short8 bl = *(const short8*)(xlds + (size_t)((4 + ks) * 64 + l) * 8);
        #pragma unroll
        for (int mt = 0; mt < 4; ++mt)
          acc[mt] = __builtin_amdgcn_mfma_f32_16x16x32_bf16(pah[mt], bh, acc[mt], 0, 0, 0);
        #pragma unroll
        for (int mt = 0; mt < 4; ++mt)
          acc[mt] = __builtin_amdgcn_mfma_f32_16x16x32_bf16(pah[mt], bl, acc[mt], 0, 0, 0);
        #pragma unroll
        for (int mt = 0; mt < 4; ++mt)
          acc[mt] = __builtin_amdgcn_mfma_f32_16x16x32_bf16(pal[mt], bh, acc[mt], 0, 0, 0);
      }

      // ---- epilogue: finalize scores, running argmax, stash into sbuf ----
      // Indices encountered in strictly increasing order per lane -> strict >
      // keeps the lowest index on ties (matches jnp.argmax).
      #pragma unroll
      for (int mt = 0; mt < 4; ++mt) {
        int pbase = chunk * 256 + w * 64 + mt * 16 + (l >> 4) * 4;
        float psa[4];
        *(float4*)psa = *(const float4*)(psq + pbase);
        f32x4 o;
        {
          #pragma clang fp contract(off)
          #pragma unroll
          for (int r = 0; r < 4; ++r) {
            float s = xs + psa[r];
            o[r] = __builtin_fmaf(2.0f, acc[mt][r], -s);
            if (o[r] > best) { best = o[r]; bidx = pbase + r; }
          }
        }
        *(f32x4*)&sbuf[l & 15][pbase - half * 512] = o;
      }
    }

    // ---- drain this half: each score row written as a 2 KB contiguous run,
    //      rows in order -> ~block-linear 32 KB burst (fill-like) ----
    barrier_lds();
    #pragma unroll
    for (int ps = 0; ps < 8; ++ps) {
      int idx = ps * 256 + tid;
      int row = idx >> 7;          // 0..15 (2 rows per step)
      int c4  = idx & 127;         // f32x4 index within the 512-col half
      f32x4 v = *(const f32x4*)&sbuf[row][c4 * 4];
      __builtin_nontemporal_store(v,
          (f32x4*)(scores + (size_t)(m0 + row) * K_PROT + half * 512) + c4);
    }
    barrier_lds();   // readers done before next half's writers overwrite sbuf
  }

  // ---- argmax reduce: butterfly over quads, then LDS over waves ----
  #pragma unroll
  for (int m = 16; m <= 32; m <<= 1) {
    float ov = __shfl_xor(best, m);
    int   oi = __shfl_xor(bidx, m);
    if (ov > best || (ov == best && oi < bidx)) { best = ov; bidx = oi; }
  }
  if (l < 16) { sv[w][l] = best; si[w][l] = bidx; }
  barrier_lds();
  if (tid < 16) {
    float v = sv[0][tid]; int bi = si[0][tid];
    #pragma unroll
    for (int e = 1; e < 4; ++e) {
      float vv = sv[e][tid]; int ii = si[e][tid];
      if (vv > v || (vv == v && ii < bi)) { v = vv; bi = ii; }
    }
    fidx[tid] = bi;
  }
  barrier_lds();

  // ---- gather matched = original fp32 prototypes[argmax] ----
  #pragma unroll
  for (int q0 = 0; q0 < 2; ++q0) {
    int q = q0 * 256 + tid;        // 0..511
    int pix = q >> 5, f4 = q & 31;
    float4 v = ((const float4*)(p + (size_t)fidx[pix] * D_DIM))[f4];
    __builtin_nontemporal_store(*(f32x4*)&v,
        (f32x4*)(matched + (size_t)(m0 + pix) * D_DIM) + f4);
  }
}

// ---------------------------------------------------------------------------
extern "C" void kernel_launch(void* const* d_in, const int* in_sizes, int n_in,
                              void* d_out, int out_size, void* d_ws, size_t ws_size,
                              hipStream_t stream) {
  const float* x = (const float*)d_in[0];   // [B,N,D] fp32
  const float* p = (const float*)d_in[1];   // [K,D]   fp32

  float* matched = (float*)d_out;                            // [B,N,D]
  float* scores  = (float*)d_out + (size_t)M_TOT * D_DIM;    // [B,N,K]

  float* psq = (float*)d_ws;
  short* pf  = (short*)((char*)d_ws + WS_PF_OFF);

  psq_kernel<<<K_PROT / 8, 256, 0, stream>>>(p, psq);
  pfrag_kernel<<<128, 256, 0, stream>>>(p, pf);              // 32768 frags / 256
  proto_mfma<<<M_TOT / 16, 256, 0, stream>>>(x, p, pf, psq, matched, scores);
}

// Round 5
// 184.672 us; speedup vs baseline: 1.1248x; 1.1217x over previous
//
#include <hip/hip_runtime.h>

typedef short short8 __attribute__((ext_vector_type(8)));
typedef float f32x4  __attribute__((ext_vector_type(4)));

constexpr int M_TOT  = 8 * 4096;   // 32768 pixels
constexpr int K_PROT = 1024;
constexpr int D_DIM  = 128;

// ws layout: xsq @0 (128 KB), psq @128K (4 KB), pfrag @132K (512 KB)
constexpr size_t WS_PSQ_OFF = (size_t)M_TOT * 4;
constexpr size_t WS_PF_OFF  = WS_PSQ_OFF + (size_t)K_PROT * 4;

__device__ inline unsigned short bf16_hi(float f) {
  unsigned u = __builtin_bit_cast(unsigned, f);
  unsigned r = u + 0x7FFFu + ((u >> 16) & 1u);   // RNE
  return (unsigned short)(r >> 16);
}
__device__ inline float bf16_tof(unsigned short h) {
  return __builtin_bit_cast(float, (unsigned)h << 16);
}

// LDS-only barrier: ds ops complete (lgkmcnt), but do NOT drain in-flight
// global stores (vmcnt) like __syncthreads() would.
__device__ inline void barrier_lds() {
  asm volatile("s_waitcnt lgkmcnt(0)\n\ts_barrier" ::: "memory");
}

// ---------------------------------------------------------------------------
// Row squared-norms for x and p (fp32, exact) -> ws
__global__ __launch_bounds__(256) void norms_kernel(
    const float* __restrict__ x, const float* __restrict__ p,
    float* __restrict__ xsq, float* __restrict__ psq) {
  int group = blockIdx.x * (blockDim.x >> 5) + (threadIdx.x >> 5);
  int lane  = threadIdx.x & 31;
  if (group >= M_TOT + K_PROT) return;
  const float* row = (group < M_TOT) ? (x + (size_t)group * D_DIM)
                                     : (p + (size_t)(group - M_TOT) * D_DIM);
  float4 v = reinterpret_cast<const float4*>(row)[lane];
  float s = v.x * v.x + v.y * v.y + v.z * v.z + v.w * v.w;
  #pragma unroll
  for (int off = 16; off > 0; off >>= 1) s += __shfl_down(s, off, 32);
  if (lane == 0) {
    if (group < M_TOT) xsq[group] = s;
    else psq[group - M_TOT] = s;
  }
}

// ---------------------------------------------------------------------------
// Pre-swizzle protos into MFMA A-fragment order, bf16 hi/lo split.
// g in [0,32768): ng=g>>9 (16-proto group), slot=(g>>6)&7 (part*4+ks), lane=g&63.
// Element: proto = ng*16 + (lane&15), k = ks*32 + (lane>>4)*8 + j.
// Grid MUST be 32768/256 = 128 blocks.
__global__ __launch_bounds__(256) void pfrag_kernel(
    const float* __restrict__ p, short* __restrict__ pf) {
  int g    = blockIdx.x * 256 + threadIdx.x;
  int lane = g & 63;
  int s    = (g >> 6) & 7;
  int ng   = g >> 9;
  int part = s >> 2, ks = s & 3;
  int proto = ng * 16 + (lane & 15);
  int k0    = ks * 32 + (lane >> 4) * 8;
  const float4* pr = (const float4*)(p + (size_t)proto * D_DIM + k0);
  float4 a = pr[0], b = pr[1];
  float e[8] = {a.x, a.y, a.z, a.w, b.x, b.y, b.z, b.w};
  short8 frag;
  #pragma unroll
  for (int j = 0; j < 8; ++j) {
    unsigned short h = bf16_hi(e[j]);
    if (part) h = bf16_hi(e[j] - bf16_tof(h));
    frag[j] = (short)h;
  }
  *(short8*)(pf + (size_t)g * 8) = frag;
}

// ---------------------------------------------------------------------------
// Main: A=protos (global frags, L2-hot), B=pixels (LDS frags). Block = 64 pix,
// 4 waves; wave w covers protos [chunk*256 + w*64, +64) over 4 chunks.
// C/D: col(lane&15)=pixel, row=(lane>>4)*4+reg = 4 consecutive protos.
// Score stores go through a 64x132 fp32 LDS staging buffer (two half-rounds)
// so every global store instr is a 512B contiguous run.
// R5: SINGLE CHANGE vs the 195.1us version — plain stores instead of
// __builtin_nontemporal_store (A/B test of the nt write path ceiling).
__global__ __launch_bounds__(256, 2) void proto_mfma(
    const float* __restrict__ x, const float* __restrict__ p,
    const short* __restrict__ pf, const float* __restrict__ xsq,
    const float* __restrict__ psq,
    float* __restrict__ matched, float* __restrict__ scores) {
  __shared__ short xlds[32 * 64 * 8];   // 32 KB: [part*16 + nt*4 + ks][lane][8]
  __shared__ float sbuf[64][132];       // 33.8 KB score staging (pad 4 -> 2-way banks)
  __shared__ float sv[4][64];
  __shared__ int   si[4][64];
  __shared__ int   fidx[64];

  const int tid = threadIdx.x;
  const int w   = tid >> 6;
  const int l   = tid & 63;
  const int m0  = blockIdx.x * 64;

  // ---- stage x tile into LDS in B-fragment order, hi/lo split (once) ----
  #pragma unroll
  for (int i = 0; i < 8; ++i) {
    int piece = i * 256 + tid;          // 0..2047
    int lane = piece & 63;
    int s = piece >> 6;                 // 0..31
    int ks = s & 3, nt = (s >> 2) & 3, part = s >> 4;
    int pix = m0 + nt * 16 + (lane & 15);
    int k0  = ks * 32 + (lane >> 4) * 8;
    const float4* xr = (const float4*)(x + (size_t)pix * D_DIM + k0);
    float4 a = xr[0], b = xr[1];
    float e[8] = {a.x, a.y, a.z, a.w, b.x, b.y, b.z, b.w};
    short8 frag;
    #pragma unroll
    for (int j = 0; j < 8; ++j) {
      unsigned short h = bf16_hi(e[j]);
      if (part) h = bf16_hi(e[j] - bf16_tof(h));
      frag[j] = (short)h;
    }
    *(short8*)(xlds + (size_t)piece * 8) = frag;
  }
  __syncthreads();

  float xs[4];
  #pragma unroll
  for (int nt = 0; nt < 4; ++nt) xs[nt] = xsq[m0 + nt * 16 + (l & 15)];

  float best[4]; int bidx[4];
  #pragma unroll
  for (int nt = 0; nt < 4; ++nt) { best[nt] = -3.4e38f; bidx[nt] = 0; }

  for (int chunk = 0; chunk < 4; ++chunk) {
    f32x4 acc[4][4];
    #pragma unroll
    for (int mt = 0; mt < 4; ++mt)
      #pragma unroll
      for (int nt = 0; nt < 4; ++nt) acc[mt][nt] = (f32x4){0.f, 0.f, 0.f, 0.f};

    const int pgbase = chunk * 16 + w * 4;

    #pragma unroll
    for (int ks = 0; ks < 4; ++ks) {
      short8 pah[4], pal[4], bh[4], bl[4];
      #pragma unroll
      for (int mt = 0; mt < 4; ++mt) {
        pah[mt] = *(const short8*)(pf + ((size_t)((pgbase + mt) * 8 + ks) * 64 + l) * 8);
        pal[mt] = *(const short8*)(pf + ((size_t)((pgbase + mt) * 8 + 4 + ks) * 64 + l) * 8);
      }
      #pragma unroll
      for (int nt = 0; nt < 4; ++nt) {
        bh[nt] = *(const short8*)(xlds + (size_t)(((nt * 4 + ks) * 64) + l) * 8);
        bl[nt] = *(const short8*)(xlds + (size_t)(((16 + nt * 4 + ks) * 64) + l) * 8);
      }
      #pragma unroll
      for (int mt = 0; mt < 4; ++mt)
        #pragma unroll
        for (int nt = 0; nt < 4; ++nt)
          acc[mt][nt] = __builtin_amdgcn_mfma_f32_16x16x32_bf16(pah[mt], bh[nt], acc[mt][nt], 0, 0, 0);
      #pragma unroll
      for (int mt = 0; mt < 4; ++mt)
        #pragma unroll
        for (int nt = 0; nt < 4; ++nt)
          acc[mt][nt] = __builtin_amdgcn_mfma_f32_16x16x32_bf16(pah[mt], bl[nt], acc[mt][nt], 0, 0, 0);
      #pragma unroll
      for (int mt = 0; mt < 4; ++mt)
        #pragma unroll
        for (int nt = 0; nt < 4; ++nt)
          acc[mt][nt] = __builtin_amdgcn_mfma_f32_16x16x32_bf16(pal[mt], bh[nt], acc[mt][nt], 0, 0, 0);
    }

    // ---- transform acc in place to final score values + running argmax ----
    #pragma unroll
    for (int mt = 0; mt < 4; ++mt) {
      int pbase = chunk * 256 + w * 64 + mt * 16 + (l >> 4) * 4;
      float psa[4];
      *(float4*)psa = *(const float4*)(psq + pbase);
      #pragma unroll
      for (int nt = 0; nt < 4; ++nt) {
        f32x4 o;
        {
          #pragma clang fp contract(off)
          #pragma unroll
          for (int r = 0; r < 4; ++r) {
            float t = (xs[nt] + psa[r]) - 2.0f * acc[mt][nt][r];
            o[r] = -t;
            if (o[r] > best[nt]) { best[nt] = o[r]; bidx[nt] = pbase + r; }
          }
        }
        acc[mt][nt] = o;   // acc now holds final scores
      }
    }

    // ---- two staging+store rounds: waves {2h,2h+1} stage cols [h*128,+128) ----
    #pragma unroll
    for (int h = 0; h < 2; ++h) {
      if ((w >> 1) == h) {
        const int colbase = (w & 1) * 64 + (l >> 4) * 4;
        #pragma unroll
        for (int mt = 0; mt < 4; ++mt)
          #pragma unroll
          for (int nt = 0; nt < 4; ++nt)
            *(f32x4*)&sbuf[nt * 16 + (l & 15)][colbase + mt * 16] = acc[mt][nt];
      }
      barrier_lds();
      const int gbase = chunk * 256 + h * 128;
      #pragma unroll
      for (int ps = 0; ps < 8; ++ps) {
        int idx = ps * 256 + tid;
        int row = idx >> 5;          // 0..63 (8 rows per pass)
        int f4  = idx & 31;          // 0..31 (128 cols / 4)
        f32x4 v = *(const f32x4*)&sbuf[row][f4 * 4];
        *((f32x4*)(scores + (size_t)(m0 + row) * K_PROT + gbase + f4 * 4)) = v;  // plain store
      }
      barrier_lds();   // readers done before next round's writers overwrite sbuf
    }
  }

  // ---- argmax reduce: butterfly over quads, then LDS over waves ----
  #pragma unroll
  for (int nt = 0; nt < 4; ++nt) {
    #pragma unroll
    for (int m = 16; m <= 32; m <<= 1) {
      float ov = __shfl_xor(best[nt], m);
      int   oi = __shfl_xor(bidx[nt], m);
      if (ov > best[nt] || (ov == best[nt] && oi < bidx[nt])) {
        best[nt] = ov; bidx[nt] = oi;
      }
    }
  }
  if (l < 16) {
    #pragma unroll
    for (int nt = 0; nt < 4; ++nt) {
      sv[w][nt * 16 + l] = best[nt];
      si[w][nt * 16 + l] = bidx[nt];
    }
  }
  __syncthreads();
  if (tid < 64) {
    float v = sv[0][tid]; int bi = si[0][tid];
    #pragma unroll
    for (int e = 1; e < 4; ++e) {
      float vv = sv[e][tid]; int ii = si[e][tid];
      if (vv > v || (vv == v && ii < bi)) { v = vv; bi = ii; }
    }
    fidx[tid] = bi;
  }
  __syncthreads();

  // ---- gather matched = original fp32 prototypes[argmax] ----
  for (int q = tid; q < 64 * 32; q += 256) {
    int pix = q >> 5, f4 = q & 31;
    float4 v = ((const float4*)(p + (size_t)fidx[pix] * D_DIM))[f4];
    *((f32x4*)(matched + (size_t)(m0 + pix) * D_DIM) + f4) = *(f32x4*)&v;  // plain store
  }
}

// ---------------------------------------------------------------------------
extern "C" void kernel_launch(void* const* d_in, const int* in_sizes, int n_in,
                              void* d_out, int out_size, void* d_ws, size_t ws_size,
                              hipStream_t stream) {
  const float* x = (const float*)d_in[0];   // [B,N,D] fp32
  const float* p = (const float*)d_in[1];   // [K,D]   fp32

  float* matched = (float*)d_out;                            // [B,N,D]
  float* scores  = (float*)d_out + (size_t)M_TOT * D_DIM;    // [B,N,K]

  float* xsq = (float*)d_ws;
  float* psq = (float*)((char*)d_ws + WS_PSQ_OFF);
  short* pf  = (short*)((char*)d_ws + WS_PF_OFF);

  {
    int rows = M_TOT + K_PROT;
    int blocks = (rows + 7) / 8;
    norms_kernel<<<blocks, 256, 0, stream>>>(x, p, xsq, psq);
  }
  pfrag_kernel<<<128, 256, 0, stream>>>(p, pf);              // 32768 frags / 256
  proto_mfma<<<M_TOT / 64, 256, 0, stream>>>(x, p, pf, xsq, psq, matched, scores);
}